// Round 15
// baseline (152.072 us; speedup 1.0000x reference)
//
#include <hip/hip_runtime.h>

#define BIGF 1e30f
#define LOG2E 1.4426950408889634f
#define LN2F 0.6931471805599453f

constexpr int NB = 16;    // batches
constexpr int NN = 512;   // N rows
constexpr int MM = 512;   // M cols
constexpr int KD = 64;    // feature dim
constexpr int WAVES = 4;                     // 256 threads, 2 rows/lane
constexpr int CSPAN = 32;                    // diagonals per barrier phase
constexpr int NSPANS = 32;
constexpr int SPW = 20;                      // spans per 128-row wave
constexpr int TPH = 5 * (WAVES - 1) + SPW;   // 35 barrier phases
constexpr int DIAGELEMS = NN * MM;

constexpr int BBPAD = 126;
constexpr int BBSTRIDE = 768;  // cols [-126, 641] at idx 126+j
constexpr int BUFD_FLOATS = WAVES * 2 * CSPAN * 128;  // 32768 (128 KiB)
constexpr int BBUF_FLOATS = WAVES * BBSTRIDE;         // 3072  (12 KiB)
constexpr int SMEM_BYTES = (BUFD_FLOATS + BBUF_FLOATS) * 4;  // 143360

// Packed anti-diagonal layout: element (i,j) [0-based] lives at
// Dsk[b*DIAGELEMS + B(s) + i],  s = i+j.
__device__ __forceinline__ int Bclosed(int s) {
  return (s <= 511) ? (s * (s + 1)) / 2
                    : DIAGELEMS - ((1023 - s) * (1024 - s)) / 2 - (s - 511);
}

// ---------------- Kernel 1: pairwise squared distances (exp2-domain) -------
__global__ __launch_bounds__(256) void pairdist_kernel(
    const float* __restrict__ X, const float* __restrict__ Y,
    float* __restrict__ Dsk) {
  const int b = blockIdx.z;
  const int i0 = blockIdx.y * 64;
  const int j0 = blockIdx.x * 64;

  __shared__ float Xs[64][65];
  __shared__ float Ys[64][65];
  __shared__ float Ds[64][66];  // stride 66: diag reads (stride 65) conflict-free

  const float* Xb = X + ((size_t)b * NN + i0) * KD;
  const float* Yb = Y + ((size_t)b * MM + j0) * KD;
  for (int k = threadIdx.x; k < 64 * KD; k += 256) {
    Xs[k >> 6][k & 63] = Xb[k];
    Ys[k >> 6][k & 63] = Yb[k];
  }
  __syncthreads();

  const int tx = threadIdx.x & 15;
  const int ty = threadIdx.x >> 4;
  const int r0 = ty * 4, c0 = tx * 4;

  float acc[4][4];
#pragma unroll
  for (int a = 0; a < 4; ++a)
#pragma unroll
    for (int e = 0; e < 4; ++e) acc[a][e] = 0.0f;

  for (int d = 0; d < KD; ++d) {
    float xv[4], yv[4];
#pragma unroll
    for (int q = 0; q < 4; ++q) xv[q] = Xs[r0 + q][d];
#pragma unroll
    for (int q = 0; q < 4; ++q) yv[q] = Ys[c0 + q][d];
#pragma unroll
    for (int a = 0; a < 4; ++a)
#pragma unroll
      for (int e = 0; e < 4; ++e) {
        float df = xv[a] - yv[e];
        acc[a][e] = fmaf(df, df, acc[a][e]);
      }
  }

#pragma unroll
  for (int a = 0; a < 4; ++a)
#pragma unroll
    for (int e = 0; e < 4; ++e)
      Ds[r0 + a][c0 + e] = fminf(acc[a][e], 10000.0f) * LOG2E;
  __syncthreads();

  // diag-major coalesced stores: wave handles diag sl, 64 lanes = 1 segment
  const int wv = threadIdx.x >> 6;
  const int ln = threadIdx.x & 63;
  float* Db = Dsk + (size_t)b * DIAGELEMS;
  for (int sl = wv; sl < 127; sl += 4) {
    const int istart = sl > 63 ? sl - 63 : 0;
    const int iend = sl < 63 ? sl : 63;
    if (ln <= iend - istart) {
      const int ig = i0 + istart + ln;  // global row
      Db[Bclosed(i0 + j0 + sl) + ig] = Ds[istart + ln][sl - istart - ln];
    }
  }
}

// up1 = lane l-1's v; lane 0 gets old[lane0] (boundary inject).
__device__ __forceinline__ float dpp_shr1_old(float oldv, float v) {
  return __int_as_float(__builtin_amdgcn_update_dpp(
      __float_as_int(oldv), __float_as_int(v), 0x138 /*WAVE_SHR1*/, 0xf, 0xf,
      false));
}

// Full-rate bit-hack exp2/log2 (Schraudolph, balanced bias) — R10-proven.
__device__ __forceinline__ float fexp2(float x) {
  x = fmaxf(x, -126.0f);
  return __int_as_float((int)fmaf(x, 8388608.0f, 1.064975338e9f));
}
__device__ __forceinline__ float flog2(float y) {
  return fmaf((float)__float_as_int(y), 1.1920929e-7f, -126.9549534f);
}

// DMA one span (32 diagonals x 128 rows = 16 KiB) for wave w into LDS.
// 16 x global_load_lds width-16: lane l covers step 2u+(l>>5),
// rows 128w + (l&31)*4 .. +3; LDS linear (verified in round 3).
__device__ __forceinline__ void dma_span(const float* __restrict__ Dskb,
                                         float* bufD, int w, int q, int lane) {
  float* dst0 = bufD + (w * 2 + (q & 1)) * (CSPAN * 128);
  const int rbase = 128 * w + (lane & 31) * 4;
  const int sub = lane >> 5;
#pragma unroll
  for (int u = 0; u < 16; ++u) {
    int s = 32 * q + 2 * u + sub;
    s = s > 1022 ? 1022 : s;
    int e = Bclosed(s) + rbase;
    e = e > DIAGELEMS - 4 ? DIAGELEMS - 4 : e;  // junk masked by activity
    __builtin_amdgcn_global_load_lds(
        (const __attribute__((address_space(1))) void*)(Dskb + e),
        (__attribute__((address_space(3))) void*)(dst0 + u * 256), 16, 0, 0);
  }
}

// One bit-hack softmin cell: n = d + m - log2(1 + 2^(m-md) + 2^(m-mx)).
#define CELL(DVAL, A, Bv, C, NOUT)                                          \
  {                                                                         \
    const float m_ = fminf(fminf((A), (Bv)), (C));                          \
    const float md_ = __builtin_amdgcn_fmed3f((A), (Bv), (C));              \
    const float mx_ = fmaxf(fmaxf((A), (Bv)), (C));                         \
    const float ss_ = (fexp2(m_ - md_) + fexp2(m_ - mx_)) + 1.0f;           \
    NOUT = ((DVAL) + m_) - flog2(ss_);                                      \
  }

// Step k: two INDEPENDENT cells (both read only pre-step state):
//   cell0 (row i0 = r0+1): up1 = dpp(lane-1's ra1) [lane0 <- boundary],
//                          up2 = prev up1 (register chain), own = ra0.
//   cell1 (row i0+1):      up1 = ra0 (pre), up2 = rb0, own = ra1.
#define STEP_CORE(K)                                                        \
  const float o1 = __int_as_float(                                          \
      __builtin_amdgcn_readlane(__float_as_int(browA), K));                 \
  const float up1 = dpp_shr1_old(o1, ra1);                                  \
  const float up2 = up2c;                                                   \
  up2c = up1;                                                               \
  float n0, n1;                                                             \
  CELL(dv[K].x, up1, up2, ra0, n0);                                         \
  CELL(dv[K].y, ra0, rb0, ra1, n1);

// ---------------- Kernel 2: soft-DTW wavefront DP (base-2 domain) ----------
// One block per batch, 4 waves x 64 lanes, 2 adjacent rows per lane
// (1 wave/SIMD). The R4 structure — the only variant whose measured time
// equaled its arithmetic chain — with the bit-hack softmin swapped in.
// Chain per step = 1 dpp + 1 cell (cells are independent).
extern __shared__ float smem[];
__global__ __launch_bounds__(256) void softdtw_kernel(
    const float* __restrict__ Dsk, float* __restrict__ out) {
  const int b = blockIdx.x;
  const int t = threadIdx.x;
  const int w = __builtin_amdgcn_readfirstlane(t >> 6);
  const int lane = t & 63;

  float* bufD = smem;                // [4][2][32][128]
  float* bbuf = smem + BUFD_FLOATS;  // [4][768]: row w col j at [w][126+j]

  for (int k = t; k < BBUF_FLOATS; k += 256) bbuf[k] = BIGF;
  __syncthreads();

  const float* __restrict__ Dskb = Dsk + (size_t)b * DIAGELEMS;

  // pre-issue DMA for this wave's first span (c = 4w, parity 0)
  dma_span(Dskb, bufD, w, 4 * w, lane);

  const int r0 = 128 * w + 2 * lane;  // 0-based top row; cells i = r0+1, r0+2
  float ra0 = BIGF, rb0 = BIGF;       // top row:    R'[i0][j-1], R'[i0][j-2]
  float ra1 = BIGF;                   // bottom row: R'[i0+1][j-1]
  // up2 chain = R'[r0][j-1] = previous step's up1; seed origin R'[0][0]=0.
  float up2c = (w == 0 && lane == 0) ? 0.0f : BIGF;

  for (int S = 0; S < TPH; ++S) {
    const int cc = S - 5 * w;  // phase-local span index
    if (cc >= 0 && cc < SPW) {
      const int c = cc + 4 * w;  // global span (<= 31)
      if (cc + 1 < SPW) {
        dma_span(Dskb, bufD, w, c + 1, lane);
        asm volatile("s_waitcnt vmcnt(16)" ::: "memory");  // span-c DMA done
      } else {
        asm volatile("s_waitcnt vmcnt(0)" ::: "memory");
      }

      // boundary row segment: browA[lane] = R'[128w][32cc+1+lane]; step k
      // consumes browA[k] (k<32) via readlane — producer is 1+ phases ahead.
      int bi = BBPAD + 32 * cc + 1 + lane;
      bi = bi > BBSTRIDE - 1 ? BBSTRIDE - 1 : bi;
      const float browA = w ? bbuf[w * BBSTRIDE + bi] : BIGF;

      // force-preload the 32 (row r0, row r0+1) pairs into 64 VGPRs
      const float* myD = bufD + (w * 2 + (c & 1)) * (CSPAN * 128);
      const __attribute__((address_space(3))) float* mp =
          (const __attribute__((address_space(3))) float*)(myD + 2 * lane);
      unsigned maddr = (unsigned)(size_t)mp;

      float2 dv[CSPAN];
      asm volatile(
          "ds_read_b64 %0, %32 offset:0\n\t"
          "ds_read_b64 %1, %32 offset:512\n\t"
          "ds_read_b64 %2, %32 offset:1024\n\t"
          "ds_read_b64 %3, %32 offset:1536\n\t"
          "ds_read_b64 %4, %32 offset:2048\n\t"
          "ds_read_b64 %5, %32 offset:2560\n\t"
          "ds_read_b64 %6, %32 offset:3072\n\t"
          "ds_read_b64 %7, %32 offset:3584\n\t"
          "ds_read_b64 %8, %32 offset:4096\n\t"
          "ds_read_b64 %9, %32 offset:4608\n\t"
          "ds_read_b64 %10, %32 offset:5120\n\t"
          "ds_read_b64 %11, %32 offset:5632\n\t"
          "ds_read_b64 %12, %32 offset:6144\n\t"
          "ds_read_b64 %13, %32 offset:6656\n\t"
          "ds_read_b64 %14, %32 offset:7168\n\t"
          "ds_read_b64 %15, %32 offset:7680\n\t"
          "ds_read_b64 %16, %32 offset:8192\n\t"
          "ds_read_b64 %17, %32 offset:8704\n\t"
          "ds_read_b64 %18, %32 offset:9216\n\t"
          "ds_read_b64 %19, %32 offset:9728\n\t"
          "ds_read_b64 %20, %32 offset:10240\n\t"
          "ds_read_b64 %21, %32 offset:10752\n\t"
          "ds_read_b64 %22, %32 offset:11264\n\t"
          "ds_read_b64 %23, %32 offset:11776\n\t"
          "ds_read_b64 %24, %32 offset:12288\n\t"
          "ds_read_b64 %25, %32 offset:12800\n\t"
          "ds_read_b64 %26, %32 offset:13312\n\t"
          "ds_read_b64 %27, %32 offset:13824\n\t"
          "ds_read_b64 %28, %32 offset:14336\n\t"
          "ds_read_b64 %29, %32 offset:14848\n\t"
          "ds_read_b64 %30, %32 offset:15360\n\t"
          "ds_read_b64 %31, %32 offset:15872\n\t"
          "s_waitcnt lgkmcnt(0)"
          : "=&v"(dv[0]), "=&v"(dv[1]), "=&v"(dv[2]), "=&v"(dv[3]),
            "=&v"(dv[4]), "=&v"(dv[5]), "=&v"(dv[6]), "=&v"(dv[7]),
            "=&v"(dv[8]), "=&v"(dv[9]), "=&v"(dv[10]), "=&v"(dv[11]),
            "=&v"(dv[12]), "=&v"(dv[13]), "=&v"(dv[14]), "=&v"(dv[15]),
            "=&v"(dv[16]), "=&v"(dv[17]), "=&v"(dv[18]), "=&v"(dv[19]),
            "=&v"(dv[20]), "=&v"(dv[21]), "=&v"(dv[22]), "=&v"(dv[23]),
            "=&v"(dv[24]), "=&v"(dv[25]), "=&v"(dv[26]), "=&v"(dv[27]),
            "=&v"(dv[28]), "=&v"(dv[29]), "=&v"(dv[30]), "=&v"(dv[31])
          : "v"(maddr)
          : "memory");

      // publish bottom-row value (row r0+2; lane63 row = 128(w+1)) unmasked:
      // junk writes land in the +-126 pad; lane 63 is the last writer of
      // every consumed column (writes ordered by lane within/across phases).
      float* pubp =
          bbuf + ((w + 1) & 3) * BBSTRIDE + (BBPAD + 32 * cc - 2 * lane);

      if (cc >= 4 && cc <= 15) {  // both cells active for all lanes/steps
#pragma unroll
        for (int k = 0; k < CSPAN; ++k) {
          STEP_CORE(k);
          rb0 = ra0;
          ra0 = n0;
          ra1 = n1;
          pubp[k] = n1;
        }
      } else {  // edge phases: activity masks
        const int jv0 = 32 * cc + 1 - 2 * lane;  // cell0 column at k=0
#pragma unroll
        for (int k = 0; k < CSPAN; ++k) {
          STEP_CORE(k);
          const bool a0 = (unsigned)(jv0 + k - 1) < (unsigned)MM;
          const bool a1 = (unsigned)(jv0 + k - 2) < (unsigned)MM;
          rb0 = a0 ? ra0 : rb0;
          ra0 = a0 ? n0 : ra0;
          ra1 = a1 ? n1 : ra1;
          pubp[k] = n1;
        }
      }
    }
    // Raw barrier: drain LDS ops (publish visibility); DMA prefetch stays
    // in flight (vmcnt-gated at its consumer).
    asm volatile("s_waitcnt lgkmcnt(0)" ::: "memory");
    __builtin_amdgcn_s_barrier();
  }

  if (w == WAVES - 1 && lane == 63) out[b] = ra1 * LN2F;  // R'[512][512]
}

extern "C" void kernel_launch(void* const* d_in, const int* in_sizes, int n_in,
                              void* d_out, int out_size, void* d_ws,
                              size_t ws_size, hipStream_t stream) {
  const float* X = (const float*)d_in[0];
  const float* Y = (const float*)d_in[1];
  float* out = (float*)d_out;
  float* Dsk = (float*)d_ws;

  const size_t needed = (size_t)NB * DIAGELEMS * sizeof(float);
  if (ws_size < needed) return;

  hipFuncSetAttribute((const void*)softdtw_kernel,
                      hipFuncAttributeMaxDynamicSharedMemorySize, SMEM_BYTES);

  pairdist_kernel<<<dim3(MM / 64, NN / 64, NB), 256, 0, stream>>>(X, Y, Dsk);
  softdtw_kernel<<<NB, 256, SMEM_BYTES, stream>>>(Dsk, out);
}